// Round 3
// baseline (293.510 us; speedup 1.0000x reference)
//
#include <hip/hip_runtime.h>

#define DM 1024
#define NSEQ 8192

typedef __attribute__((ext_vector_type(8))) short short8;
typedef __attribute__((ext_vector_type(4))) float floatx4;

// pack two fp32 -> bf16x2 (round-to-nearest via +0x8000), 3 VALU ops
__device__ __forceinline__ unsigned pk_rn(float a, float b) {
  return __builtin_amdgcn_perm(__float_as_uint(b) + 0x8000u,
                               __float_as_uint(a) + 0x8000u, 0x07060302u);
}

// Fused kernel: one block per (b,s,h) tile. 512 threads = 8 waves, each wave
// owns 64 q rows. LDS map (16B units):
//   [0,4096)     KT: unit R*8 + (c8 ^ (R&7)) holds K[R][8*c8 .. +8], R = 0..511
//   [4096,6144)  VT chunk double-buffer: buf*1024 + u16*64 + dp holds
//                V^T[d = dp ^ (u16&7)][kk = c*128 + 8*u16 .. +8] (chunk-local)
//   [6144,7168)  P strips: 128 units per wave (32 q at a time, double-pumped)
// Total 7168 * 16B = 112 KB (<= 128 KB known-good static LDS on gfx950).
// Grid 512 = 1 block/CU x 2 rounds.

// Build V^T for one 128-kk chunk out of swizzled KT (row-broadcast LDS reads,
// conflict-free: per wave, kk row is fixed; 64 lanes span the 64 d-slots).
__device__ __forceinline__ void build_vt(uint4* smem, int tid, int c, int buf) {
  const unsigned short* Ts = (const unsigned short*)smem;
  uint4* vb = &smem[4096 + buf * 1024];
  #pragma unroll
  for (int p = 0; p < 2; ++p) {
    int m = p * 512 + tid;                   // 0..1023 chunk-local unit
    int u16 = m >> 6, dp = m & 63;
    int d = dp ^ (u16 & 7);
    unsigned v[8];
    #pragma unroll
    for (int j = 0; j < 8; ++j) {
      int kk = c * 128 + 8 * u16 + j;        // kk & 7 == j
      v[j] = Ts[(kk * 8 + ((d >> 3) ^ j)) * 8 + (d & 7)];
    }
    uint4 pk;
    pk.x = v[0] | (v[1] << 16);
    pk.y = v[2] | (v[3] << 16);
    pk.z = v[4] | (v[5] << 16);
    pk.w = v[6] | (v[7] << 16);
    vb[m] = pk;
  }
}

__global__ __launch_bounds__(512, 2)
void fused_kernel(const float* __restrict__ x, float* __restrict__ out) {
  __shared__ uint4 smem[7168];
  const int tau = blockIdx.x;                  // 512 = b(4) * s(8) * h(16)
  const int b = tau >> 7, s = (tau >> 4) & 7, h = tau & 15;
  const float* xb = x + ((size_t)b * NSEQ + s * 1024) * DM + h * 64;
  float* ob = out + ((size_t)b * NSEQ + s * 1024) * DM + h * 64;
  const int tid = threadIdx.x;
  const int lane = tid & 63;
  const int wu = __builtin_amdgcn_readfirstlane(tid >> 6);

  // ---- stage: gather even rows, fp32->bf16, swizzled KT; zero odd rows ----
  {
    const int c8 = tid & 7, rr = tid >> 3;     // rr 0..63
    float4 A[8], B[8];
    #pragma unroll
    for (int p = 0; p < 8; ++p) {
      int r = p * 64 + rr;
      const float* src = xb + (size_t)(2 * r) * DM + c8 * 8;
      A[p] = *(const float4*)src;
      B[p] = *(const float4*)(src + 4);
    }
    const float4 z = make_float4(0.f, 0.f, 0.f, 0.f);
    #pragma unroll
    for (int p = 0; p < 8; ++p) {
      int r = p * 64 + rr;
      float* zp = ob + (size_t)(2 * r + 1) * DM + c8 * 8;
      *(float4*)zp = z;
      *(float4*)(zp + 4) = z;
    }
    #pragma unroll
    for (int p = 0; p < 8; ++p) {
      int r = p * 64 + rr;
      uint4 pk;
      pk.x = pk_rn(A[p].x, A[p].y); pk.y = pk_rn(A[p].z, A[p].w);
      pk.z = pk_rn(B[p].x, B[p].y); pk.w = pk_rn(B[p].z, B[p].w);
      smem[r * 8 + (c8 ^ (r & 7))] = pk;
    }
  }
  __syncthreads();

  const int cq = lane & 15, u = lane >> 4;
  const int qw0 = wu * 64;

  // Q fragments straight from swizzled KT (stable after first barrier)
  short8 qf[4][2];
  #pragma unroll
  for (int qs = 0; qs < 4; ++qs) {
    int R = qw0 + qs * 16 + cq;
    #pragma unroll
    for (int ksd = 0; ksd < 2; ++ksd)
      qf[qs][ksd] = *(const short8*)&smem[R * 8 + ((4 * ksd + u) ^ (cq & 7))];
  }

  // VT for chunk 0 into buf 0
  build_vt(smem, tid, 0, 0);
  __syncthreads();

  floatx4 o[4][4];
  #pragma unroll
  for (int qs = 0; qs < 4; ++qs)
    #pragma unroll
    for (int nt = 0; nt < 4; ++nt) o[qs][nt] = (floatx4){0.f, 0.f, 0.f, 0.f};
  float l[4] = {0.f, 0.f, 0.f, 0.f};
  const float cf = 0.125f * 1.44269504088896340736f;  // scale * log2(e)

  unsigned short* Pw = (unsigned short*)&smem[6144 + wu * 128];
  const int pswz = u ^ (cq & 3);

  for (int c = 0; c < 4; ++c) {
    // overlap: build next chunk's VT into the other buffer
    if (c < 3) build_vt(smem, tid, c + 1, (c + 1) & 1);
    const uint4* vbase = &smem[4096 + (c & 1) * 1024];

    #pragma unroll
    for (int ks = 0; ks < 4; ++ks) {
      // S^T strip: m = kk (32 rows), n = q (4 x 16)
      floatx4 acc[4][2];
      #pragma unroll
      for (int qs = 0; qs < 4; ++qs)
        #pragma unroll
        for (int t = 0; t < 2; ++t) acc[qs][t] = (floatx4){0.f, 0.f, 0.f, 0.f};
      #pragma unroll
      for (int t = 0; t < 2; ++t) {
        int R = c * 128 + 32 * ks + 16 * t + cq;   // R & 7 == cq & 7
        #pragma unroll
        for (int ksd = 0; ksd < 2; ++ksd) {
          short8 af = *(short8*)&smem[R * 8 + ((4 * ksd + u) ^ (cq & 7))];
          #pragma unroll
          for (int qs = 0; qs < 4; ++qs)
            acc[qs][t] = __builtin_amdgcn_mfma_f32_16x16x32_bf16(af, qf[qs][ksd], acc[qs][t], 0, 0, 0);
        }
      }
      // V^T fragments for this strip (chunk-local u16, shared across all qs)
      const int u16 = 4 * ks + u;
      short8 vfr[4];
      #pragma unroll
      for (int nt = 0; nt < 4; ++nt)
        vfr[nt] = *(const short8*)&vbase[u16 * 64 + 16 * nt + (cq ^ (u16 & 7))];
      // exp + pack + PV, two 32-q halves through the 2KB P strip
      #pragma unroll
      for (int qp = 0; qp < 2; ++qp) {
        #pragma unroll
        for (int q2 = 0; q2 < 2; ++q2) {
          int qs = 2 * qp + q2;
          #pragma unroll
          for (int t = 0; t < 2; ++t) {
            float p0 = __builtin_amdgcn_exp2f(acc[qs][t][0] * cf);
            float p1 = __builtin_amdgcn_exp2f(acc[qs][t][1] * cf);
            float p2 = __builtin_amdgcn_exp2f(acc[qs][t][2] * cf);
            float p3 = __builtin_amdgcn_exp2f(acc[qs][t][3] * cf);
            l[qs] += (p0 + p1) + (p2 + p3);
            uint2 w2;
            w2.x = pk_rn(p0, p1);
            w2.y = pk_rn(p2, p3);
            int unit = (q2 * 16 + cq) * 4 + ((2 * t + (u >> 1)) ^ (cq & 3));
            *(uint2*)(Pw + unit * 8 + (u & 1) * 4) = w2;
          }
        }
        #pragma unroll
        for (int q2 = 0; q2 < 2; ++q2) {
          int qs = 2 * qp + q2;
          short8 pf = *(short8*)(Pw + ((q2 * 16 + cq) * 4 + pswz) * 8);
          #pragma unroll
          for (int nt = 0; nt < 4; ++nt)
            o[qs][nt] = __builtin_amdgcn_mfma_f32_16x16x32_bf16(pf, vfr[nt], o[qs][nt], 0, 0, 0);
        }
      }
    }
    // rotation barrier: VT[c+1] complete; everyone done reading buf[c&1]
    if (c < 3) __syncthreads();
  }

  // ---- softmax denominator + epilogue (O: col d = nt*16+cq, row q = 4u+r) ----
  #pragma unroll
  for (int qs = 0; qs < 4; ++qs) {
    float lf = l[qs];
    lf += __shfl_xor(lf, 16, 64);
    lf += __shfl_xor(lf, 32, 64);
    #pragma unroll
    for (int r = 0; r < 4; ++r) {
      float linv = 1.f / __shfl(lf, 4 * u + r, 64);
      float* orow = ob + (size_t)(2 * (qw0 + qs * 16 + 4 * u + r)) * DM + cq;
      #pragma unroll
      for (int nt = 0; nt < 4; ++nt)
        orow[nt * 16] = o[qs][nt][r] * linv;
    }
  }
}

extern "C" void kernel_launch(void* const* d_in, const int* in_sizes, int n_in,
                              void* d_out, int out_size, void* d_ws, size_t ws_size,
                              hipStream_t stream) {
  const float* x = (const float*)d_in[0];
  float* out = (float*)d_out;
  fused_kernel<<<dim3(512), dim3(512), 0, stream>>>(x, out);
}